// Round 1
// baseline (295.956 us; speedup 1.0000x reference)
//
#include <hip/hip_runtime.h>
#include <hip/hip_bf16.h>

#define S_LEN 4096
#define DK    64
#define BQ    64
#define BK    64
#define NWAVE 4

typedef __bf16 bf16x8 __attribute__((ext_vector_type(8)));
typedef float  f32x4  __attribute__((ext_vector_type(4)));

__device__ __forceinline__ short f2bf(float f) {
    __bf16 h = (__bf16)f;
    union { __bf16 h; short s; } u; u.h = h; return u.s;
}

// Flash attention, causal, scale=1/64, pad-mask (s==0 -> -inf), fp32 in/out.
// Each block: 64 Q rows of one batch. 4 waves x 16 rows. K-tiles of 64 keys.
__global__ __launch_bounds__(256, 2) void attn_kernel(
    const float* __restrict__ Q, const float* __restrict__ K,
    const float* __restrict__ V, float* __restrict__ O)
{
    __shared__ __align__(16) short Ks[BK * DK];        // [key][dk] bf16, swizzled
    __shared__ __align__(16) short Vts[DK * BK];       // [dk][key] bf16, swizzled
    __shared__ __align__(16) short Ps[NWAVE][16 * BK]; // per-wave P [qrow16][key] swizzled

    const int tid  = threadIdx.x;
    const int wave = tid >> 6;
    const int lane = tid & 63;
    const int lg   = lane >> 4;   // 16-lane group 0..3
    const int lr   = lane & 15;
    const int dk0  = lg * 8;      // contiguous-8 k slice per lane group

    const int batch = blockIdx.y;
    const int qb    = gridDim.x - 1 - blockIdx.x;  // big-qb blocks first (balance)
    const int q0    = qb * BQ;

    const size_t bo = (size_t)batch * S_LEN * DK;
    const float* Qb = Q + bo;
    const float* Kb = K + bo;
    const float* Vb = V + bo;

    // Q fragments (A operand): lane holds row (q0+16*wave+lr), dk = 32*s + dk0 + e
    bf16x8 qf[2];
    {
        const float* Qr = Qb + (size_t)(q0 + 16 * wave + lr) * DK;
        #pragma unroll
        for (int s = 0; s < 2; ++s) {
            const float4 a = *reinterpret_cast<const float4*>(Qr + 32 * s + dk0);
            const float4 b = *reinterpret_cast<const float4*>(Qr + 32 * s + dk0 + 4);
            qf[s][0] = (__bf16)a.x; qf[s][1] = (__bf16)a.y;
            qf[s][2] = (__bf16)a.z; qf[s][3] = (__bf16)a.w;
            qf[s][4] = (__bf16)b.x; qf[s][5] = (__bf16)b.y;
            qf[s][6] = (__bf16)b.z; qf[s][7] = (__bf16)b.w;
        }
    }

    const float NEG_INF = -__builtin_inff();
    float m_run[4], l_run[4];
    f32x4 oa[4];
    #pragma unroll
    for (int r = 0; r < 4; ++r) { m_run[r] = NEG_INF; l_run[r] = 0.f; }
    #pragma unroll
    for (int u = 0; u < 4; ++u) oa[u] = (f32x4){0.f, 0.f, 0.f, 0.f};

    const int rowq = q0 + 16 * wave + 4 * lg; // + r gives this lane's acc rows
    const int ntiles = qb + 1;

    for (int kt = 0; kt < ntiles; ++kt) {
        const int k0 = kt * BK;
        __syncthreads();  // protect prev-tile LDS reads before overwrite

        // ---- stage K tile [64 keys][64 dk] and V^T tile [64 dk][64 keys], bf16 + XOR swizzle
        {
            const float* Kt = Kb + (size_t)k0 * DK;
            const float* Vg = Vb + (size_t)k0 * DK;
            #pragma unroll
            for (int i = 0; i < 4; ++i) {
                const int e   = i * 1024 + tid * 4;
                const int row = e >> 6, col = e & 63;
                {
                    const float4 f = *reinterpret_cast<const float4*>(Kt + e);
                    short4 sp;
                    sp.x = f2bf(f.x); sp.y = f2bf(f.y); sp.z = f2bf(f.z); sp.w = f2bf(f.w);
                    const int cs = col ^ ((row & 7) << 3);
                    *reinterpret_cast<short4*>(&Ks[row * 64 + cs]) = sp;
                }
                {
                    const float4 f = *reinterpret_cast<const float4*>(Vg + e);
                    const float fa[4] = {f.x, f.y, f.z, f.w};
                    #pragma unroll
                    for (int j = 0; j < 4; ++j) {
                        const int d = col + j;  // dk index
                        Vts[d * 64 + (row ^ ((d & 7) << 3))] = f2bf(fa[j]);
                    }
                }
            }
        }
        __syncthreads();

        // ---- S = Q K^T  (16 q-rows x 64 keys per wave)
        f32x4 sa[4];
        #pragma unroll
        for (int t = 0; t < 4; ++t) {
            sa[t] = (f32x4){0.f, 0.f, 0.f, 0.f};
            const int krow = 16 * t + lr;  // B operand: key j = lr
            #pragma unroll
            for (int s = 0; s < 2; ++s) {
                const int cs = (32 * s + dk0) ^ ((krow & 7) << 3);
                const bf16x8 kf = *reinterpret_cast<const bf16x8*>(&Ks[krow * 64 + cs]);
                sa[t] = __builtin_amdgcn_mfma_f32_16x16x32_bf16(qf[s], kf, sa[t], 0, 0, 0);
            }
        }

        // ---- masks + online softmax (C/D layout: col=lr key, row=4*lg+r)
        float spv[4][4];
        float mt[4] = {NEG_INF, NEG_INF, NEG_INF, NEG_INF};
        #pragma unroll
        for (int t = 0; t < 4; ++t) {
            const int key = k0 + 16 * t + lr;
            #pragma unroll
            for (int r = 0; r < 4; ++r) {
                float x = sa[t][r] * (1.0f / 64.0f);
                if (x == 0.0f) x = NEG_INF;        // pad mask (faithful to ref)
                if (key > rowq + r) x = NEG_INF;   // causal mask
                spv[t][r] = x;
                mt[r] = fmaxf(mt[r], x);
            }
        }
        #pragma unroll
        for (int off = 8; off >= 1; off >>= 1)
            #pragma unroll
            for (int r = 0; r < 4; ++r)
                mt[r] = fmaxf(mt[r], __shfl_xor(mt[r], off));

        float alpha[4], psum[4];
        #pragma unroll
        for (int r = 0; r < 4; ++r) {
            const float mnew = fmaxf(m_run[r], mt[r]);
            // guard -inf - -inf = NaN; if m_run==-inf, oa is still 0 so alpha moot
            alpha[r] = (m_run[r] == NEG_INF) ? 0.f : __expf(m_run[r] - mnew);
            m_run[r] = mnew;
            psum[r] = 0.f;
        }
        short pb[4][4];
        #pragma unroll
        for (int t = 0; t < 4; ++t)
            #pragma unroll
            for (int r = 0; r < 4; ++r) {
                const float x = spv[t][r];
                const float p = (x == NEG_INF) ? 0.f : __expf(x - m_run[r]);
                psum[r] += p;
                pb[t][r] = f2bf(p);
            }
        #pragma unroll
        for (int off = 8; off >= 1; off >>= 1)
            #pragma unroll
            for (int r = 0; r < 4; ++r)
                psum[r] += __shfl_xor(psum[r], off);
        #pragma unroll
        for (int r = 0; r < 4; ++r)
            l_run[r] = alpha[r] * l_run[r] + psum[r];
        #pragma unroll
        for (int u = 0; u < 4; ++u)
            #pragma unroll
            for (int r = 0; r < 4; ++r)
                oa[u][r] *= alpha[r];

        // ---- P -> LDS (per-wave buffer, swizzled). Wave-local DS ops are in-order.
        short* Pw = &Ps[wave][0];
        #pragma unroll
        for (int r = 0; r < 4; ++r) {
            const int prow = 4 * lg + r;
            #pragma unroll
            for (int t = 0; t < 4; ++t)
                Pw[prow * 64 + ((16 * t + lr) ^ ((prow & 7) << 3))] = pb[t][r];
        }

        // ---- O += P V   (A = P[16x64], B = V[64 keys x 64 dk] via V^T LDS)
        bf16x8 pa[2];
        #pragma unroll
        for (int s = 0; s < 2; ++s) {
            const int cs = (32 * s + dk0) ^ ((lr & 7) << 3);
            pa[s] = *reinterpret_cast<const bf16x8*>(&Pw[lr * 64 + cs]);
        }
        #pragma unroll
        for (int u = 0; u < 4; ++u) {
            const int vrow = 16 * u + lr;  // dk output col = lr (B operand j)
            #pragma unroll
            for (int s = 0; s < 2; ++s) {
                const int cs = (32 * s + dk0) ^ ((vrow & 7) << 3);
                const bf16x8 vbf = *reinterpret_cast<const bf16x8*>(&Vts[vrow * 64 + cs]);
                oa[u] = __builtin_amdgcn_mfma_f32_16x16x32_bf16(pa[s], vbf, oa[u], 0, 0, 0);
            }
        }
    }

    // ---- epilogue: O / l  (l==0 -> 0, matches ref NaN cleanup)
    float inv[4];
    #pragma unroll
    for (int r = 0; r < 4; ++r) inv[r] = (l_run[r] > 0.f) ? (1.0f / l_run[r]) : 0.f;
    float* Ob = O + bo + (size_t)(q0 + 16 * wave) * DK;
    #pragma unroll
    for (int u = 0; u < 4; ++u)
        #pragma unroll
        for (int r = 0; r < 4; ++r)
            Ob[(size_t)(4 * lg + r) * DK + 16 * u + lr] = oa[u][r] * inv[r];
}

extern "C" void kernel_launch(void* const* d_in, const int* in_sizes, int n_in,
                              void* d_out, int out_size, void* d_ws, size_t ws_size,
                              hipStream_t stream) {
    (void)in_sizes; (void)n_in; (void)d_ws; (void)ws_size; (void)out_size;
    const float* q = (const float*)d_in[0];
    const float* k = (const float*)d_in[1];
    const float* v = (const float*)d_in[2];
    float* o = (float*)d_out;
    dim3 grid(S_LEN / BQ, 8);
    dim3 block(256);
    hipLaunchKernelGGL(attn_kernel, grid, block, 0, stream, q, k, v, o);
}

// Round 2
// 132.982 us; speedup vs baseline: 2.2255x; 2.2255x over previous
//
#include <hip/hip_runtime.h>
#include <hip/hip_bf16.h>

#define S_LEN 4096
#define DK    64
#define BQ    64
#define BK    64

typedef __bf16 bf16x8 __attribute__((ext_vector_type(8)));
typedef float  f32x4  __attribute__((ext_vector_type(4)));

__device__ __forceinline__ short f2bf(float f) {
    union { __bf16 h; short s; } u; u.h = (__bf16)f; return u.s;
}

// Flash attention, causal, scale=1/64 (folded into Q), pad-mask (s==0 -> -inf).
// Pipelined: prefetch tile t+1 K/V into regs during compute of tile t,
// write to double-buffered LDS after compute. One barrier per tile.
__global__ __launch_bounds__(256, 2) void attn_kernel(
    const float* __restrict__ Q, const float* __restrict__ K,
    const float* __restrict__ V, float* __restrict__ O)
{
    __shared__ __align__(16) short Ks[2][BK * DK];   // [key][dk] bf16, swizzled
    __shared__ __align__(16) short Vts[2][DK * BK];  // [dk][key] bf16, swizzled
    __shared__ __align__(16) short Ps[4][16 * BK];   // per-wave P, swizzled

    const int tid  = threadIdx.x;
    const int wave = tid >> 6;
    const int lane = tid & 63;
    const int lg   = lane >> 4;
    const int lr   = lane & 15;
    const int dk0  = lg * 8;

    const int batch = blockIdx.y;
    const int qb    = gridDim.x - 1 - blockIdx.x;  // heavy blocks dispatch first
    const int q0    = qb * BQ;
    const size_t bo = (size_t)batch * S_LEN * DK;
    const float* Kb = K + bo;
    const float* Vb = V + bo;

    // staging coordinates
    const int srow = tid >> 4;         // 0..15
    const int scol = (tid & 15) * 4;   // 0..60
    const int vr0  = (tid >> 4) * 4;   // 0..60 (V 4x4 transpose block)

    float4 kreg[4];
    float  vregf[4][4];  // [j][e] = V[vr0+j][scol+e]

    auto load_tile = [&](int k0) {
        const float* Kt = Kb + (size_t)k0 * DK;
        const float* Vt = Vb + (size_t)k0 * DK;
        #pragma unroll
        for (int i = 0; i < 4; ++i)
            kreg[i] = *reinterpret_cast<const float4*>(Kt + (i * 16 + srow) * DK + scol);
        #pragma unroll
        for (int j = 0; j < 4; ++j) {
            const float4 f = *reinterpret_cast<const float4*>(Vt + (vr0 + j) * DK + scol);
            vregf[j][0] = f.x; vregf[j][1] = f.y; vregf[j][2] = f.z; vregf[j][3] = f.w;
        }
    };

    auto store_tile = [&](int b) {
        short* Kd = &Ks[b][0];
        short* Vd = &Vts[b][0];
        #pragma unroll
        for (int i = 0; i < 4; ++i) {
            const int row = i * 16 + srow;
            short4 sp;
            sp.x = f2bf(kreg[i].x); sp.y = f2bf(kreg[i].y);
            sp.z = f2bf(kreg[i].z); sp.w = f2bf(kreg[i].w);
            *reinterpret_cast<short4*>(&Kd[row * 64 + (scol ^ ((row & 7) << 3))]) = sp;
        }
        #pragma unroll
        for (int j2 = 0; j2 < 4; ++j2) {
            const int d = scol + j2;  // dk index (V^T row)
            short4 sp;
            sp.x = f2bf(vregf[0][j2]); sp.y = f2bf(vregf[1][j2]);
            sp.z = f2bf(vregf[2][j2]); sp.w = f2bf(vregf[3][j2]);
            *reinterpret_cast<short4*>(&Vd[d * 64 + (vr0 ^ ((d & 7) << 3))]) = sp;
        }
    };

    // Q fragments with 1/64 scale folded in
    bf16x8 qf[2];
    {
        const float* Qr = Q + bo + (size_t)(q0 + 16 * wave + lr) * DK;
        #pragma unroll
        for (int s = 0; s < 2; ++s) {
            const float4 a = *reinterpret_cast<const float4*>(Qr + 32 * s + dk0);
            const float4 b = *reinterpret_cast<const float4*>(Qr + 32 * s + dk0 + 4);
            qf[s][0] = (__bf16)(a.x * 0.015625f); qf[s][1] = (__bf16)(a.y * 0.015625f);
            qf[s][2] = (__bf16)(a.z * 0.015625f); qf[s][3] = (__bf16)(a.w * 0.015625f);
            qf[s][4] = (__bf16)(b.x * 0.015625f); qf[s][5] = (__bf16)(b.y * 0.015625f);
            qf[s][6] = (__bf16)(b.z * 0.015625f); qf[s][7] = (__bf16)(b.w * 0.015625f);
        }
    }

    const float NEG_INF = -__builtin_inff();
    float m_run[4], l_run[4];
    f32x4 oa[4];
    #pragma unroll
    for (int r = 0; r < 4; ++r) { m_run[r] = NEG_INF; l_run[r] = 0.f; }
    #pragma unroll
    for (int u = 0; u < 4; ++u) oa[u] = (f32x4){0.f, 0.f, 0.f, 0.f};

    const int rowq   = q0 + 16 * wave + 4 * lg;
    const int ntiles = qb + 1;

    // prologue: tile 0 into buf 0
    load_tile(0);
    store_tile(0);
    __syncthreads();

    for (int kt = 0; kt < ntiles; ++kt) {
        const int cur = kt & 1;
        const bool pf = (kt + 1 < ntiles);
        if (pf) load_tile((kt + 1) * BK);   // issue loads; latency hides under compute

        const short* Kc = &Ks[cur][0];
        const short* Vc = &Vts[cur][0];
        const int k0 = kt * BK;
        const bool diag = (kt == qb);

        // ---- S = Q K^T
        f32x4 sa[4];
        #pragma unroll
        for (int t = 0; t < 4; ++t) {
            sa[t] = (f32x4){0.f, 0.f, 0.f, 0.f};
            const int krow = 16 * t + lr;
            const int swz  = (krow & 7) << 3;
            #pragma unroll
            for (int s = 0; s < 2; ++s) {
                const bf16x8 kf = *reinterpret_cast<const bf16x8*>(&Kc[krow * 64 + ((32 * s + dk0) ^ swz)]);
                sa[t] = __builtin_amdgcn_mfma_f32_16x16x32_bf16(qf[s], kf, sa[t], 0, 0, 0);
            }
        }

        // ---- masks + online softmax (l kept lane-partial; reduced in epilogue)
        float spv[4][4];
        float mt[4] = {NEG_INF, NEG_INF, NEG_INF, NEG_INF};
        #pragma unroll
        for (int t = 0; t < 4; ++t) {
            const int key = k0 + 16 * t + lr;
            #pragma unroll
            for (int r = 0; r < 4; ++r) {
                float x = sa[t][r];
                x = (x == 0.0f) ? NEG_INF : x;                 // pad mask
                if (diag && key > rowq + r) x = NEG_INF;       // causal (diag tile only)
                spv[t][r] = x;
                mt[r] = fmaxf(mt[r], x);
            }
        }
        #pragma unroll
        for (int off = 8; off >= 1; off >>= 1)
            #pragma unroll
            for (int r = 0; r < 4; ++r)
                mt[r] = fmaxf(mt[r], __shfl_xor(mt[r], off));

        float alpha[4];
        #pragma unroll
        for (int r = 0; r < 4; ++r) {
            const float mnew = fmaxf(m_run[r], mt[r]);
            alpha[r] = (m_run[r] == NEG_INF) ? 0.f : __expf(m_run[r] - mnew);
            m_run[r] = mnew;
        }
        short pb[4][4];
        float psum[4] = {0.f, 0.f, 0.f, 0.f};
        #pragma unroll
        for (int t = 0; t < 4; ++t)
            #pragma unroll
            for (int r = 0; r < 4; ++r) {
                const float x = spv[t][r];
                const float p = (x == NEG_INF) ? 0.f : __expf(x - m_run[r]);
                psum[r] += p;
                pb[t][r] = f2bf(p);
            }
        #pragma unroll
        for (int r = 0; r < 4; ++r)
            l_run[r] = alpha[r] * l_run[r] + psum[r];
        #pragma unroll
        for (int u = 0; u < 4; ++u)
            #pragma unroll
            for (int r = 0; r < 4; ++r)
                oa[u][r] *= alpha[r];

        // ---- P -> per-wave LDS (wave-local, in-order)
        short* Pw = &Ps[wave][0];
        #pragma unroll
        for (int r = 0; r < 4; ++r) {
            const int prow = 4 * lg + r;
            const int swz  = (prow & 7) << 3;
            #pragma unroll
            for (int t = 0; t < 4; ++t)
                Pw[prow * 64 + ((16 * t + lr) ^ swz)] = pb[t][r];
        }

        // ---- O += P V
        bf16x8 pa[2];
        #pragma unroll
        for (int s = 0; s < 2; ++s)
            pa[s] = *reinterpret_cast<const bf16x8*>(&Pw[lr * 64 + ((32 * s + dk0) ^ ((lr & 7) << 3))]);
        #pragma unroll
        for (int u = 0; u < 4; ++u) {
            const int vrow = 16 * u + lr;
            const int swz  = (vrow & 7) << 3;
            #pragma unroll
            for (int s = 0; s < 2; ++s) {
                const bf16x8 vbf = *reinterpret_cast<const bf16x8*>(&Vc[vrow * 64 + ((32 * s + dk0) ^ swz)]);
                oa[u] = __builtin_amdgcn_mfma_f32_16x16x32_bf16(pa[s], vbf, oa[u], 0, 0, 0);
            }
        }

        // ---- write prefetched tile to the other buffer, then one barrier
        if (pf) store_tile(cur ^ 1);
        __syncthreads();
    }

    // ---- epilogue: reduce l across the 16-lane group, then O / l
    #pragma unroll
    for (int off = 8; off >= 1; off >>= 1)
        #pragma unroll
        for (int r = 0; r < 4; ++r)
            l_run[r] += __shfl_xor(l_run[r], off);
    float inv[4];
    #pragma unroll
    for (int r = 0; r < 4; ++r) inv[r] = (l_run[r] > 0.f) ? (1.0f / l_run[r]) : 0.f;
    float* Ob = O + bo + (size_t)(q0 + 16 * wave) * DK;
    #pragma unroll
    for (int u = 0; u < 4; ++u)
        #pragma unroll
        for (int r = 0; r < 4; ++r)
            Ob[(size_t)(4 * lg + r) * DK + 16 * u + lr] = oa[u][r] * inv[r];
}

extern "C" void kernel_launch(void* const* d_in, const int* in_sizes, int n_in,
                              void* d_out, int out_size, void* d_ws, size_t ws_size,
                              hipStream_t stream) {
    (void)in_sizes; (void)n_in; (void)d_ws; (void)ws_size; (void)out_size;
    const float* q = (const float*)d_in[0];
    const float* k = (const float*)d_in[1];
    const float* v = (const float*)d_in[2];
    float* o = (float*)d_out;
    dim3 grid(S_LEN / BQ, 8);
    dim3 block(256);
    hipLaunchKernelGGL(attn_kernel, grid, block, 0, stream, q, k, v, o);
}

// Round 4
// 88.842 us; speedup vs baseline: 3.3313x; 1.4968x over previous
//
#include <hip/hip_runtime.h>
#include <hip/hip_bf16.h>

#define S_LEN 4096
#define DK    64
#define BQ    64
#define BK    64

typedef __bf16 bf16x8 __attribute__((ext_vector_type(8)));
typedef float  f32x4  __attribute__((ext_vector_type(4)));

__device__ __forceinline__ short f2bf(float f) {
    union { __bf16 h; short s; } u; u.h = (__bf16)f; return u.s;
}
__device__ __forceinline__ float bf2f(short s) {
    union { float f; unsigned u; } u; u.u = ((unsigned)(unsigned short)s) << 16; return u.f;
}

// Flash attention, causal, scale=1/64 (folded into Q), pad-mask (s==0 -> -inf).
// 256 blocks x 512 threads. Block x of batch b handles q-tiles (63-x) and (x):
// constant 65 k-tiles/block -> perfect balance. 8 waves = 2 key-split groups x
// 4 q-subtiles; group g computes k-tile 2p+g; groups merge (m,l,O) at q-tile end.
__global__ __launch_bounds__(512, 2) void attn_kernel(
    const float* __restrict__ Q, const float* __restrict__ K,
    const float* __restrict__ V, float* __restrict__ O)
{
    __shared__ __align__(16) short Ks[2][BK * DK];   // [tile-in-pair][key][dk] swizzled
    __shared__ __align__(16) short Vts[2][DK * BK];  // [tile-in-pair][dk][key] swizzled
    __shared__ __align__(16) short Ps[8][16 * BK];   // per-wave P / merge-O buffers
    __shared__ float Ml[4][16][2];                    // merge m,l from group 1

    const int tid  = threadIdx.x;
    const int wave = tid >> 6;
    const int lane = tid & 63;
    const int lg   = lane >> 4;
    const int lr   = lane & 15;
    const int dk0  = lg * 8;
    const int grp  = wave >> 2;   // key-split group 0/1
    const int qsub = wave & 3;    // 16-row q sub-tile

    const int batch = blockIdx.y;
    const size_t bo = (size_t)batch * S_LEN * DK;
    const float* Kb = K + bo;
    const float* Vb = V + bo;

    // staging coords: 512 threads stage a PAIR of 64x64 tiles (K and V^T)
    const int stt  = tid >> 8;         // tile within pair
    const int sidx = tid & 255;
    const int skr  = sidx >> 4;        // 0..15
    const int skc  = (sidx & 15) * 4;  // 0..60

    float4 kreg[4], vreg[4];

    auto load_pair = [&](int kbase) {
        const float* Kt = Kb + (size_t)(kbase + stt * BK) * DK;
        const float* Vt = Vb + (size_t)(kbase + stt * BK) * DK;
        #pragma unroll
        for (int i = 0; i < 4; ++i)
            kreg[i] = *reinterpret_cast<const float4*>(Kt + (i * 16 + skr) * DK + skc);
        #pragma unroll
        for (int j = 0; j < 4; ++j)
            vreg[j] = *reinterpret_cast<const float4*>(Vt + (skr * 4 + j) * DK + skc);
    };
    auto store_pair = [&]() {
        short* Kd = &Ks[stt][0];
        short* Vd = &Vts[stt][0];
        #pragma unroll
        for (int i = 0; i < 4; ++i) {
            const int row = i * 16 + skr;
            short4 sp;
            sp.x = f2bf(kreg[i].x); sp.y = f2bf(kreg[i].y);
            sp.z = f2bf(kreg[i].z); sp.w = f2bf(kreg[i].w);
            *reinterpret_cast<short4*>(&Kd[row * 64 + (skc ^ ((row & 7) << 3))]) = sp;
        }
        const int key0 = skr * 4;  // V^T: 4x4 transpose block
        #pragma unroll
        for (int j2 = 0; j2 < 4; ++j2) {
            const int d = skc + j2;
            short4 sp;
            sp.x = f2bf(reinterpret_cast<const float*>(&vreg[0])[j2]);
            sp.y = f2bf(reinterpret_cast<const float*>(&vreg[1])[j2]);
            sp.z = f2bf(reinterpret_cast<const float*>(&vreg[2])[j2]);
            sp.w = f2bf(reinterpret_cast<const float*>(&vreg[3])[j2]);
            *reinterpret_cast<short4*>(&Vd[d * 64 + (key0 ^ ((d & 7) << 3))]) = sp;
        }
    };

    const float NEG_INF = -__builtin_inff();

    #pragma unroll 1
    for (int qi = 0; qi < 2; ++qi) {
        const int qb = qi ? (int)blockIdx.x : 63 - (int)blockIdx.x;
        const int q0 = qb * BQ;
        const int ntiles = qb + 1;
        const int npairs = (ntiles + 1) >> 1;

        // Q fragments with 1/64 folded in
        bf16x8 qf[2];
        {
            const float* Qr = Q + bo + (size_t)(q0 + 16 * qsub + lr) * DK;
            #pragma unroll
            for (int s = 0; s < 2; ++s) {
                const float4 a = *reinterpret_cast<const float4*>(Qr + 32 * s + dk0);
                const float4 b = *reinterpret_cast<const float4*>(Qr + 32 * s + dk0 + 4);
                qf[s][0] = (__bf16)(a.x * 0.015625f); qf[s][1] = (__bf16)(a.y * 0.015625f);
                qf[s][2] = (__bf16)(a.z * 0.015625f); qf[s][3] = (__bf16)(a.w * 0.015625f);
                qf[s][4] = (__bf16)(b.x * 0.015625f); qf[s][5] = (__bf16)(b.y * 0.015625f);
                qf[s][6] = (__bf16)(b.z * 0.015625f); qf[s][7] = (__bf16)(b.w * 0.015625f);
            }
        }

        float m_run[4], l_run[4];
        f32x4 oa[4];
        #pragma unroll
        for (int r = 0; r < 4; ++r) { m_run[r] = NEG_INF; l_run[r] = 0.f; }
        #pragma unroll
        for (int u = 0; u < 4; ++u) oa[u] = (f32x4){0.f, 0.f, 0.f, 0.f};

        const int rowq = q0 + 16 * qsub + 4 * lg;

        load_pair(0);
        store_pair();
        __syncthreads();

        for (int p = 0; p < npairs; ++p) {
            const int kt = 2 * p + grp;
            if (p + 1 < npairs) load_pair((p + 1) * 2 * BK);  // latency hides under compute

            if (kt < ntiles) {
                const short* Kc = &Ks[grp][0];
                const short* Vc = &Vts[grp][0];
                const int k0 = kt * BK;
                const bool diag = (kt == qb);

                // S = Q K^T
                f32x4 sa[4];
                #pragma unroll
                for (int t = 0; t < 4; ++t) {
                    sa[t] = (f32x4){0.f, 0.f, 0.f, 0.f};
                    const int krow = 16 * t + lr;
                    const int swz  = (krow & 7) << 3;
                    #pragma unroll
                    for (int s = 0; s < 2; ++s) {
                        const bf16x8 kf = *reinterpret_cast<const bf16x8*>(&Kc[krow * 64 + ((32 * s + dk0) ^ swz)]);
                        sa[t] = __builtin_amdgcn_mfma_f32_16x16x32_bf16(qf[s], kf, sa[t], 0, 0, 0);
                    }
                }

                // masks + online softmax (l lane-partial until merge)
                float spv[4][4];
                float mt[4] = {NEG_INF, NEG_INF, NEG_INF, NEG_INF};
                #pragma unroll
                for (int t = 0; t < 4; ++t) {
                    const int key = k0 + 16 * t + lr;
                    #pragma unroll
                    for (int r = 0; r < 4; ++r) {
                        float x = sa[t][r];
                        x = (x == 0.0f) ? NEG_INF : x;             // pad mask
                        if (diag && key > rowq + r) x = NEG_INF;   // causal (diag tile)
                        spv[t][r] = x;
                        mt[r] = fmaxf(mt[r], x);
                    }
                }
                #pragma unroll
                for (int off = 8; off >= 1; off >>= 1)
                    #pragma unroll
                    for (int r = 0; r < 4; ++r)
                        mt[r] = fmaxf(mt[r], __shfl_xor(mt[r], off));

                float alpha[4];
                #pragma unroll
                for (int r = 0; r < 4; ++r) {
                    const float mnew = fmaxf(m_run[r], mt[r]);
                    alpha[r] = (m_run[r] == NEG_INF) ? 0.f : __expf(m_run[r] - mnew);
                    m_run[r] = mnew;
                }
                short pb[4][4];
                float psum[4] = {0.f, 0.f, 0.f, 0.f};
                #pragma unroll
                for (int t = 0; t < 4; ++t)
                    #pragma unroll
                    for (int r = 0; r < 4; ++r) {
                        const float x = spv[t][r];
                        const float pv = (x == NEG_INF) ? 0.f : __expf(x - m_run[r]);
                        psum[r] += pv;
                        pb[t][r] = f2bf(pv);
                    }
                #pragma unroll
                for (int r = 0; r < 4; ++r)
                    l_run[r] = alpha[r] * l_run[r] + psum[r];
                #pragma unroll
                for (int u = 0; u < 4; ++u)
                    #pragma unroll
                    for (int r = 0; r < 4; ++r)
                        oa[u][r] *= alpha[r];

                // P -> per-wave LDS (wave-local, in-order)
                short* Pw = &Ps[wave][0];
                #pragma unroll
                for (int r = 0; r < 4; ++r) {
                    const int prow = 4 * lg + r;
                    const int swz  = (prow & 7) << 3;
                    #pragma unroll
                    for (int t = 0; t < 4; ++t)
                        Pw[prow * 64 + ((16 * t + lr) ^ swz)] = pb[t][r];
                }

                // O += P V
                bf16x8 pa[2];
                #pragma unroll
                for (int s = 0; s < 2; ++s)
                    pa[s] = *reinterpret_cast<const bf16x8*>(&Pw[lr * 64 + ((32 * s + dk0) ^ ((lr & 7) << 3))]);
                #pragma unroll
                for (int u = 0; u < 4; ++u) {
                    const int vrow = 16 * u + lr;
                    const int swz  = (vrow & 7) << 3;
                    #pragma unroll
                    for (int s = 0; s < 2; ++s) {
                        const bf16x8 vbf = *reinterpret_cast<const bf16x8*>(&Vc[vrow * 64 + ((32 * s + dk0) ^ swz)]);
                        oa[u] = __builtin_amdgcn_mfma_f32_16x16x32_bf16(pa[s], vbf, oa[u], 0, 0, 0);
                    }
                }
            }

            __syncthreads();                                   // KV reads done
            if (p + 1 < npairs) { store_pair(); __syncthreads(); }  // KV writes visible
        }

        // ---- merge key-split groups: reduce l, exchange (m,l,O) via LDS
        #pragma unroll
        for (int off = 8; off >= 1; off >>= 1)
            #pragma unroll
            for (int r = 0; r < 4; ++r)
                l_run[r] += __shfl_xor(l_run[r], off);

        short* Obuf = &Ps[4 + qsub][0];  // group-1 wave's own P buffer
        if (grp == 1) {
            #pragma unroll
            for (int r = 0; r < 4; ++r) {
                const int row = 4 * lg + r;
                #pragma unroll
                for (int u = 0; u < 4; ++u)
                    Obuf[row * 64 + 16 * u + lr] = f2bf(oa[u][r]);
                if (lr == 0) { Ml[qsub][row][0] = m_run[r]; Ml[qsub][row][1] = l_run[r]; }
            }
        }
        __syncthreads();
        if (grp == 0) {
            float* Ob = O + bo + (size_t)(q0 + 16 * qsub) * DK;
            #pragma unroll
            for (int r = 0; r < 4; ++r) {
                const int row = 4 * lg + r;
                const float m1 = Ml[qsub][row][0];
                const float l1 = Ml[qsub][row][1];
                const float mm = fmaxf(m_run[r], m1);
                const float a0 = (m_run[r] == NEG_INF) ? 0.f : __expf(m_run[r] - mm);
                const float a1 = (m1 == NEG_INF) ? 0.f : __expf(m1 - mm);
                const float lt = a0 * l_run[r] + a1 * l1;
                const float inv = (lt > 0.f) ? (1.0f / lt) : 0.f;
                #pragma unroll
                for (int u = 0; u < 4; ++u) {
                    const float o1 = bf2f(Obuf[row * 64 + 16 * u + lr]);
                    Ob[(size_t)row * DK + 16 * u + lr] = (a0 * oa[u][r] + a1 * o1) * inv;
                }
            }
        }
        __syncthreads();  // protect merge buffers before next q-tile
    }
}

extern "C" void kernel_launch(void* const* d_in, const int* in_sizes, int n_in,
                              void* d_out, int out_size, void* d_ws, size_t ws_size,
                              hipStream_t stream) {
    (void)in_sizes; (void)n_in; (void)d_ws; (void)ws_size; (void)out_size;
    const float* q = (const float*)d_in[0];
    const float* k = (const float*)d_in[1];
    const float* v = (const float*)d_in[2];
    float* o = (float*)d_out;
    dim3 grid(32, 8);
    dim3 block(512);
    hipLaunchKernelGGL(attn_kernel, grid, block, 0, stream, q, k, v, o);
}